// Round 18
// baseline (210.450 us; speedup 1.0000x reference)
//
#include <hip/hip_runtime.h>
#include <hip/hip_bf16.h>
#include <stdint.h>

// LoRA int8-dequant linear, MI355X/gfx950 — LoRA folded into W pre-quant.
//   W_eff = qweight*scale + 2*B@A ; sw[o] = scale[o] + margin
//   Wi8 = rne(W_eff / sw) (exact-range by margin), Xi8 = rne(x*127/absmax_row)
//   out = (Xi8 @ Wi8^T)_i32 * (tstep[m] * sw[o])
// GEMM = R17 cross-barrier-pipelined kernel (best measured, 132 us), epilogue
// reduced to drain+scale+store. lora_xa kernel and GEMM LoRA epilogue gone.

typedef __bf16 bf16x8 __attribute__((ext_vector_type(8)));
typedef float f32x4 __attribute__((ext_vector_type(4)));
typedef int i32x4 __attribute__((ext_vector_type(4)));

#define DIN   4096
#define DOUT  4096
#define MTOT  8192
#define RNK   64
#define NT    64

__device__ inline void gload_lds16(const void* g, void* l) {
  __builtin_amdgcn_global_load_lds((const __attribute__((address_space(1))) void*)g,
                                   (__attribute__((address_space(3))) void*)l,
                                   16, 0, 0);
}

// ==== prep: [0,8192) quant x rows; [8192,8256) A -> At^T (f32);
//            [8256,8512) Blt = bf16(2*lora_B) ====
__global__ __launch_bounds__(256) void prep_kernel(const float* __restrict__ x,
                                                   const float* __restrict__ lA,
                                                   const float* __restrict__ lB,
                                                   signed char* __restrict__ Xi8,
                                                   float* __restrict__ tstep,
                                                   float* __restrict__ At,
                                                   __bf16* __restrict__ Blt) {
  const int bid = blockIdx.x, t = threadIdx.x;
  if (bid < 8192) {
    const int row = bid;
    const float4* xr = (const float4*)(x + (size_t)row * DIN);
    float4 v[4];
    float m = 0.f;
#pragma unroll
    for (int s = 0; s < 4; ++s) {
      v[s] = xr[t + s * 256];
      m = fmaxf(m, fmaxf(fmaxf(fabsf(v[s].x), fabsf(v[s].y)),
                         fmaxf(fabsf(v[s].z), fabsf(v[s].w))));
    }
#pragma unroll
    for (int off = 32; off > 0; off >>= 1) m = fmaxf(m, __shfl_xor(m, off));
    __shared__ float wm[4];
    if ((t & 63) == 0) wm[t >> 6] = m;
    __syncthreads();
    m = fmaxf(fmaxf(wm[0], wm[1]), fmaxf(wm[2], wm[3]));
    m = fmaxf(m, 1e-30f);
    const float rs = 127.0f / m;
    int* orow = (int*)(Xi8 + (size_t)row * DIN);
#pragma unroll
    for (int s = 0; s < 4; ++s) {
      float e[4] = {v[s].x, v[s].y, v[s].z, v[s].w};
      union { signed char c[4]; int i; } p;
#pragma unroll
      for (int j = 0; j < 4; ++j) {
        int q = __float2int_rn(e[j] * rs);
        q = q > 127 ? 127 : (q < -127 ? -127 : q);
        p.c[j] = (signed char)q;
      }
      orow[t + s * 256] = p.i;
    }
    if (t == 0) tstep[row] = m * (1.0f / 127.0f);
  } else if (bid < 8256) {
    const int r = bid - 8192;   // A row 0..63
#pragma unroll 4
    for (int c0 = t * 4; c0 < DIN; c0 += 1024) {
      float4 v = *(const float4*)(lA + (size_t)r * DIN + c0);
      At[(size_t)(c0 + 0) * RNK + r] = v.x;
      At[(size_t)(c0 + 1) * RNK + r] = v.y;
      At[(size_t)(c0 + 2) * RNK + r] = v.z;
      At[(size_t)(c0 + 3) * RNK + r] = v.w;
    }
  } else {
    int i = (bid - 8256) * 256 + t;
    float4 v = ((const float4*)lB)[i];
    union { __bf16 h[4]; uint64_t u; } p;
    p.h[0] = (__bf16)(2.0f * v.x); p.h[1] = (__bf16)(2.0f * v.y);
    p.h[2] = (__bf16)(2.0f * v.z); p.h[3] = (__bf16)(2.0f * v.w);
    ((uint64_t*)Blt)[i] = p.u;
  }
}

// ==== fold_w: Wi8 = rne((qweight*scale + Blt@At^T) / sw), sw = scale+margin ====
// 1024 blocks (32x32 tiles of 128x128). 4 waves; wave w: rows w*32..w*32+31.
// lora via mfma_f32_16x16x32_bf16 (verified lora_xa operand pattern: A-op =
// Blt rows [K-contig], B-op = At rows [K-contig]); scatter to padded LDS;
// pass 2: coalesced qweight read + requant + coalesced Wi8 write.
__global__ __launch_bounds__(256) void fold_w_kernel(const int* __restrict__ qw,
                                                     const float* __restrict__ scale,
                                                     const float* __restrict__ At,
                                                     const __bf16* __restrict__ Blt,
                                                     signed char* __restrict__ Wi8,
                                                     float* __restrict__ sw) {
  __shared__ float lds[128][129];
  const int t = threadIdx.x, lane = t & 63, w = t >> 6;
  const int bx = blockIdx.x & 31, by = blockIdx.x >> 5;
  const size_t m0 = (size_t)by * 128, n0 = (size_t)bx * 128;

  f32x4 acc[2][8] = {};
  const int kof = (lane >> 4) * 8;
#pragma unroll
  for (int ks = 0; ks < 2; ++ks) {
    const int k0 = ks * 32 + kof;
    bf16x8 af[2];
#pragma unroll
    for (int mi = 0; mi < 2; ++mi)
      af[mi] = *(const bf16x8*)(Blt + (m0 + w * 32 + mi * 16 + (lane & 15)) * RNK + k0);
#pragma unroll
    for (int ni = 0; ni < 8; ++ni) {
      const float* ap = At + (n0 + ni * 16 + (lane & 15)) * RNK + k0;
      float4 v0 = *(const float4*)ap;
      float4 v1 = *(const float4*)(ap + 4);
      bf16x8 bfv = {(__bf16)v0.x, (__bf16)v0.y, (__bf16)v0.z, (__bf16)v0.w,
                    (__bf16)v1.x, (__bf16)v1.y, (__bf16)v1.z, (__bf16)v1.w};
#pragma unroll
      for (int mi = 0; mi < 2; ++mi)
        acc[mi][ni] = __builtin_amdgcn_mfma_f32_16x16x32_bf16(af[mi], bfv, acc[mi][ni], 0, 0, 0);
    }
  }
#pragma unroll
  for (int mi = 0; mi < 2; ++mi)
#pragma unroll
    for (int ni = 0; ni < 8; ++ni)
#pragma unroll
      for (int j = 0; j < 4; ++j)
        lds[w * 32 + mi * 16 + (lane >> 4) * 4 + j][ni * 16 + (lane & 15)] = acc[mi][ni][j];
  __syncthreads();

  // pass 2: thread t -> row r = t>>1, cols (t&1)*64 .. +64
  const int r = t >> 1, c0 = (t & 1) * 64;
  const size_t o = m0 + r;
  const float sc = scale[o];
  const float step = sc + 6e-4f;          // margin covers |2BA| <= 0.076
  const float rstep = 1.0f / step;
  if (bx == 0 && (t & 1) == 0) sw[o] = step;
  const int* qrow = qw + o * DIN + n0 + c0;
  signed char* wrow = Wi8 + o * DIN + n0 + c0;
#pragma unroll
  for (int c = 0; c < 64; c += 4) {
    int4 q4 = *(const int4*)(qrow + c);
    union { signed char c4[4]; int i; } p;
    int e;
    e = __float2int_rn(((float)q4.x * sc + lds[r][c0 + c + 0]) * rstep);
    p.c4[0] = (signed char)(e > 127 ? 127 : (e < -127 ? -127 : e));
    e = __float2int_rn(((float)q4.y * sc + lds[r][c0 + c + 1]) * rstep);
    p.c4[1] = (signed char)(e > 127 ? 127 : (e < -127 ? -127 : e));
    e = __float2int_rn(((float)q4.z * sc + lds[r][c0 + c + 2]) * rstep);
    p.c4[2] = (signed char)(e > 127 ? 127 : (e < -127 ? -127 : e));
    e = __float2int_rn(((float)q4.w * sc + lds[r][c0 + c + 3]) * rstep);
    p.c4[3] = (signed char)(e > 127 ? 127 : (e < -127 ? -127 : e));
    *(int*)(wrow + c) = p.i;
  }
}

// ==== i8 main GEMM (R17 cross-barrier pipeline), slim epilogue ====
// LDS 128 KB: 4 bufs x 32 KB, buf = { A0(8K rows0-127), A1(8K), B0, B1 }.
// Half = 128 rows x 64 i8; row r, 16B-slot s at phys slot s ^ ((r>>1)&3).
// Body(kt): hi(kt-1); stage(kt+3); a2-read(kt); prefetch lo+B(kt+1);
// lo(kt); lgkmcnt(0); vmcnt(4); barrier.
__global__ __launch_bounds__(512, 1) void gemm_i8_kernel(const signed char* __restrict__ Xi8,
                                                         const signed char* __restrict__ Wi8,
                                                         const float* __restrict__ sw,
                                                         const float* __restrict__ tstep,
                                                         float* __restrict__ out) {
  extern __shared__ char smem[];
  const int tid = threadIdx.x;
  const int lane = tid & 63;
  const int w = tid >> 6;
  const int wr = w >> 2;
  const int wc = w & 3;

  const int swz = (blockIdx.x & 7) * 64 + (blockIdx.x >> 3);
  const int bx = swz & 15;
  const int by = swz >> 4;
  const size_t bm = (size_t)by * 256, bn = (size_t)bx * 256;

  const int rc = ((lane >> 4) ^ ((lane >> 1) & 3)) << 4;
  const int srow = tid >> 2;
  const int scol = ((tid & 3) ^ ((tid >> 3) & 3)) << 4;

  auto SH = [&](const signed char* g, size_t r0, int srct, int ldsoff) {
    gload_lds16(g + (r0 + srow) * (size_t)4096 + srct * 64 + scol,
                smem + ldsoff + tid * 16);
  };
  auto stage = [&](int srct, int buf) {
    int b = buf * 32768;
    SH(Xi8, bm, srct, b); SH(Xi8, bm + 128, srct, b + 8192);
    SH(Wi8, bn, srct, b + 16384); SH(Wi8, bn + 128, srct, b + 24576);
  };

  const int aoffw = wr * 8192 + (lane & 15) * 64 + rc;
  const int boffw = 16384 + (wc >> 1) * 8192 + (wc & 1) * 4096 + (lane & 15) * 64 + rc;

  i32x4 aP[4], bP[4], aQ[4], bQ[4], a2P[4], a2Q[4];
  i32x4 acc[8][4] = {};

  stage(0, 0); stage(1, 1); stage(2, 2);
  asm volatile("s_waitcnt vmcnt(4)" ::: "memory");
  __builtin_amdgcn_s_barrier();
#pragma unroll
  for (int mi = 0; mi < 4; ++mi) aP[mi] = *(const i32x4*)(smem + aoffw + mi * 1024);
#pragma unroll
  for (int ni = 0; ni < 4; ++ni) bP[ni] = *(const i32x4*)(smem + boffw + ni * 1024);

  auto body = [&](int kt, i32x4 (&AY)[4], i32x4 (&BY)[4],
                  i32x4 (&AX)[4], i32x4 (&BX)[4],
                  i32x4 (&a2Y)[4], i32x4 (&a2X)[4], bool doHi) {
    if (doHi) {
#pragma unroll
      for (int mi = 0; mi < 4; ++mi)
#pragma unroll
        for (int ni = 0; ni < 4; ++ni)
          acc[4 + mi][ni] = __builtin_amdgcn_mfma_i32_16x16x64_i8(a2X[mi], BX[ni], acc[4 + mi][ni], 0, 0, 0);
    }
    const int st = (kt + 3 < NT) ? kt + 3 : NT - 1;
    stage(st, (kt + 3) & 3);
    const int ab = (kt & 3) * 32768 + aoffw;
#pragma unroll
    for (int mi = 0; mi < 4; ++mi)
      a2Y[mi] = *(const i32x4*)(smem + ab + 4096 + mi * 1024);
    if (kt + 1 < NT) {
      const int nb = ((kt + 1) & 3) * 32768;
#pragma unroll
      for (int mi = 0; mi < 4; ++mi) AX[mi] = *(const i32x4*)(smem + nb + aoffw + mi * 1024);
#pragma unroll
      for (int ni = 0; ni < 4; ++ni) BX[ni] = *(const i32x4*)(smem + nb + boffw + ni * 1024);
    }
#pragma unroll
    for (int mi = 0; mi < 4; ++mi)
#pragma unroll
      for (int ni = 0; ni < 4; ++ni)
        acc[mi][ni] = __builtin_amdgcn_mfma_i32_16x16x64_i8(AY[mi], BY[ni], acc[mi][ni], 0, 0, 0);
    asm volatile("s_waitcnt lgkmcnt(0)" ::: "memory");
    __builtin_amdgcn_sched_barrier(0);
    asm volatile("s_waitcnt vmcnt(4)" ::: "memory");
    __builtin_amdgcn_s_barrier();
  };

  body(0, aP, bP, aQ, bQ, a2P, a2Q, false);
  for (int kt = 1; kt < NT - 1; kt += 2) {
    body(kt, aQ, bQ, aP, bP, a2Q, a2P, true);
    body(kt + 1, aP, bP, aQ, bQ, a2P, a2Q, true);
  }
  body(NT - 1, aQ, bQ, aP, bP, a2Q, a2P, true);
#pragma unroll
  for (int mi = 0; mi < 4; ++mi)
#pragma unroll
    for (int ni = 0; ni < 4; ++ni)
      acc[4 + mi][ni] = __builtin_amdgcn_mfma_i32_16x16x64_i8(a2Q[mi], bQ[ni], acc[4 + mi][ni], 0, 0, 0);

  // ---- slim epilogue: drain dummy stages, scale, store ----
  asm volatile("s_waitcnt vmcnt(0)" ::: "memory");

  float sc[4];
#pragma unroll
  for (int ni = 0; ni < 4; ++ni)
    sc[ni] = sw[bn + wc * 64 + ni * 16 + (lane & 15)];
  f32x4 tm[8];
#pragma unroll
  for (int mi = 0; mi < 8; ++mi)
    tm[mi] = *(const f32x4*)&tstep[bm + wr * 128 + mi * 16 + (lane >> 4) * 4];

#pragma unroll
  for (int mi = 0; mi < 8; ++mi) {
    const size_t row = bm + wr * 128 + mi * 16 + (lane >> 4) * 4;
#pragma unroll
    for (int ni = 0; ni < 4; ++ni) {
      const size_t col = bn + wc * 64 + ni * 16 + (lane & 15);
#pragma unroll
      for (int j = 0; j < 4; ++j)
        out[(row + j) * DOUT + col] = (float)acc[mi][ni][j] * (sc[ni] * tm[mi][j]);
    }
  }
}

extern "C" void kernel_launch(void* const* d_in, const int* in_sizes, int n_in,
                              void* d_out, int out_size, void* d_ws, size_t ws_size,
                              hipStream_t stream) {
  const float* x = (const float*)d_in[0];
  const int* qw = (const int*)d_in[1];
  const float* scale = (const float*)d_in[2];
  const float* lA = (const float*)d_in[3];
  const float* lB = (const float*)d_in[4];
  float* out = (float*)d_out;

  char* ws = (char*)d_ws;
  signed char* Xi8 = (signed char*)ws;                              // 33.55 MB
  signed char* Wi8 = (signed char*)(ws + 33554432);                 // 16.78 MB
  float* At    = (float*)(ws + 50331648);                           // 1.05 MB
  __bf16* Blt  = (__bf16*)(ws + 51380224);                          // 0.52 MB
  float* tstep = (float*)(ws + 51904512);                           // 32 KB
  float* sw    = (float*)(ws + 51937280);                           // 16 KB

  hipFuncSetAttribute((const void*)gemm_i8_kernel,
                      hipFuncAttributeMaxDynamicSharedMemorySize, 131072);

  prep_kernel<<<8512, 256, 0, stream>>>(x, lA, lB, Xi8, tstep, At, Blt);
  fold_w_kernel<<<1024, 256, 0, stream>>>(qw, scale, At, Blt, Wi8, sw);
  gemm_i8_kernel<<<(MTOT / 256) * (DOUT / 256), 512, 131072, stream>>>(
      Xi8, Wi8, sw, tstep, out);
}

// Round 19
// 198.177 us; speedup vs baseline: 1.0619x; 1.0619x over previous
//
#include <hip/hip_runtime.h>
#include <hip/hip_bf16.h>
#include <stdint.h>

// LoRA int8-dequant linear, MI355X/gfx950 — int8, cross-barrier MFMA pipeline.
// (R17 exact revert — session best: total 198.05 us, GEMM 132.1 us.)
//   Xi8[8192][4096] = rne(x * 127/absmax_row),  tstep[m] = absmax_row/127
//   Wi8[4096][4096] = qweight codes (exact i8)
//   out = (Xi8 @ Wi8^T)_i32 * (tstep[m]*scale[o]) + xa @ (2B)^T
// Main GEMM: 256x256 tile, BK=64, 8 waves, mfma_i32_16x16x64_i8, 4-deep LDS,
// counted vmcnt(4), MFMA-hi cluster pipelined across the barrier.

typedef __bf16 bf16x8 __attribute__((ext_vector_type(8)));
typedef float f32x4 __attribute__((ext_vector_type(4)));
typedef int i32x4 __attribute__((ext_vector_type(4)));

#define DIN   4096
#define DOUT  4096
#define MTOT  8192
#define RNK   64
#define NT    64

__device__ inline void gload_lds16(const void* g, void* l) {
  __builtin_amdgcn_global_load_lds((const __attribute__((address_space(1))) void*)g,
                                   (__attribute__((address_space(3))) void*)l,
                                   16, 0, 0);
}

// ==== merged prep: blocks [0,8192) quant x rows; [8192,8256) quant lora_A
// rows; [8256,8512) Blt = bf16(2*lora_B); [8512,24896) Wi8 = i8(qweight) ====
__global__ __launch_bounds__(256) void prep_kernel(const float* __restrict__ x,
                                                   const int* __restrict__ qw,
                                                   const float* __restrict__ lA,
                                                   const float* __restrict__ lB,
                                                   signed char* __restrict__ Xi8,
                                                   float* __restrict__ tstep,
                                                   signed char* __restrict__ Wi8,
                                                   signed char* __restrict__ Ai8,
                                                   float* __restrict__ astep,
                                                   __bf16* __restrict__ Blt) {
  const int bid = blockIdx.x, t = threadIdx.x;
  const float* src = nullptr;
  signed char* dst = nullptr;
  float* stp = nullptr;
  int row = 0;
  if (bid < 8192) { src = x; dst = Xi8; stp = tstep; row = bid; }
  else if (bid < 8256) { src = lA; dst = Ai8; stp = astep; row = bid - 8192; }
  if (src) {
    const float4* xr = (const float4*)(src + (size_t)row * DIN);
    float4 v[4];
    float m = 0.f;
#pragma unroll
    for (int s = 0; s < 4; ++s) {
      v[s] = xr[t + s * 256];
      m = fmaxf(m, fmaxf(fmaxf(fabsf(v[s].x), fabsf(v[s].y)),
                         fmaxf(fabsf(v[s].z), fabsf(v[s].w))));
    }
#pragma unroll
    for (int off = 32; off > 0; off >>= 1) m = fmaxf(m, __shfl_xor(m, off));
    __shared__ float wm[4];
    if ((t & 63) == 0) wm[t >> 6] = m;
    __syncthreads();
    m = fmaxf(fmaxf(wm[0], wm[1]), fmaxf(wm[2], wm[3]));
    m = fmaxf(m, 1e-30f);
    const float rs = 127.0f / m;
    int* orow = (int*)(dst + (size_t)row * DIN);
#pragma unroll
    for (int s = 0; s < 4; ++s) {
      float e[4] = {v[s].x, v[s].y, v[s].z, v[s].w};
      union { signed char c[4]; int i; } p;
#pragma unroll
      for (int j = 0; j < 4; ++j) {
        int q = __float2int_rn(e[j] * rs);
        q = q > 127 ? 127 : (q < -127 ? -127 : q);
        p.c[j] = (signed char)q;
      }
      orow[t + s * 256] = p.i;
    }
    if (t == 0) stp[row] = m * (1.0f / 127.0f);
  } else if (bid < 8512) {
    int i = (bid - 8256) * 256 + t;
    float4 v = ((const float4*)lB)[i];
    union { __bf16 h[4]; uint64_t u; } p;
    p.h[0] = (__bf16)(2.0f * v.x); p.h[1] = (__bf16)(2.0f * v.y);
    p.h[2] = (__bf16)(2.0f * v.z); p.h[3] = (__bf16)(2.0f * v.w);
    ((uint64_t*)Blt)[i] = p.u;
  } else {
    int i = (bid - 8512) * 256 + t;
    int4 v = ((const int4*)qw)[i];
    union { signed char c[4]; int i; } p;
    p.c[0] = (signed char)v.x; p.c[1] = (signed char)v.y;
    p.c[2] = (signed char)v.z; p.c[3] = (signed char)v.w;
    ((int*)Wi8)[i] = p.i;
  }
}

// ---- xa = (Xi8 @ Ai8^T)*tstep*astep -> bf16 [8192][64] ----
__global__ __launch_bounds__(256) void lora_xa_kernel(const signed char* __restrict__ Xi8,
                                                      const float* __restrict__ tstep,
                                                      const signed char* __restrict__ Ai8,
                                                      const float* __restrict__ astep,
                                                      __bf16* __restrict__ xa) {
  __shared__ i32x4 red[4][64][4];
  const int w = threadIdx.x >> 6, lane = threadIdx.x & 63;
  const int rowbase = blockIdx.x * 16;
  i32x4 acc[4] = {};
  const int k00 = w * 1024 + (lane >> 4) * 16;
  const signed char* xrow = Xi8 + (size_t)(rowbase + (lane & 15)) * DIN + k00;
  const signed char* ab = Ai8 + (size_t)(lane & 15) * DIN + k00;
#pragma unroll 4
  for (int k = 0; k < 1024; k += 64) {
    i32x4 af = *(const i32x4*)(xrow + k);
#pragma unroll
    for (int ni = 0; ni < 4; ++ni) {
      i32x4 bv = *(const i32x4*)(ab + (size_t)ni * 16 * DIN + k);
      acc[ni] = __builtin_amdgcn_mfma_i32_16x16x64_i8(af, bv, acc[ni], 0, 0, 0);
    }
  }
#pragma unroll
  for (int ni = 0; ni < 4; ++ni) red[w][lane][ni] = acc[ni];
  __syncthreads();
  if (w == 0) {
    f32x4 tm = *(const f32x4*)&tstep[rowbase + (lane >> 4) * 4];
#pragma unroll
    for (int ni = 0; ni < 4; ++ni) {
      i32x4 s = red[0][lane][ni];
#pragma unroll
      for (int u = 1; u < 4; ++u) s += red[u][lane][ni];
      const int col = ni * 16 + (lane & 15);
      const float as = astep[col];
#pragma unroll
      for (int j = 0; j < 4; ++j) {
        int row = rowbase + (lane >> 4) * 4 + j;
        xa[(size_t)row * RNK + col] = (__bf16)((float)s[j] * tm[j] * as);
      }
    }
  }
}

// ==== i8 main GEMM, cross-barrier pipelined ====
// LDS 128 KB: 4 bufs x 32 KB, buf = { A0(8K rows0-127), A1(8K), B0, B1 }.
// Half = 128 rows x 64 i8; row r, 16B-slot s at phys slot s ^ ((r>>1)&3).
// Body(kt): hi(kt-1) [a2-other + B-other regs, both read last body];
// stage(kt+3)->buf[(kt+3)&3]; a2-read(kt); prefetch lo+B(kt+1)->other set;
// lo(kt) [reg-ready]; lgkmcnt(0); vmcnt(4); barrier.
__global__ __launch_bounds__(512, 1) void gemm_i8_kernel(const signed char* __restrict__ Xi8,
                                                         const signed char* __restrict__ Wi8,
                                                         const float* __restrict__ scale,
                                                         const float* __restrict__ tstep,
                                                         const __bf16* __restrict__ xa,
                                                         const __bf16* __restrict__ Blt,
                                                         float* __restrict__ out) {
  extern __shared__ char smem[];
  const int tid = threadIdx.x;
  const int lane = tid & 63;
  const int w = tid >> 6;
  const int wr = w >> 2;
  const int wc = w & 3;

  const int swz = (blockIdx.x & 7) * 64 + (blockIdx.x >> 3);
  const int bx = swz & 15;
  const int by = swz >> 4;
  const size_t bm = (size_t)by * 256, bn = (size_t)bx * 256;

  const int rc = ((lane >> 4) ^ ((lane >> 1) & 3)) << 4;
  const int srow = tid >> 2;
  const int scol = ((tid & 3) ^ ((tid >> 3) & 3)) << 4;

  auto SH = [&](const signed char* g, size_t r0, int srct, int ldsoff) {
    gload_lds16(g + (r0 + srow) * (size_t)4096 + srct * 64 + scol,
                smem + ldsoff + tid * 16);
  };
  auto stage = [&](int srct, int buf) {
    int b = buf * 32768;
    SH(Xi8, bm, srct, b); SH(Xi8, bm + 128, srct, b + 8192);
    SH(Wi8, bn, srct, b + 16384); SH(Wi8, bn + 128, srct, b + 24576);
  };

  const int aoffw = wr * 8192 + (lane & 15) * 64 + rc;
  const int boffw = 16384 + (wc >> 1) * 8192 + (wc & 1) * 4096 + (lane & 15) * 64 + rc;

  i32x4 aP[4], bP[4], aQ[4], bQ[4], a2P[4], a2Q[4];
  i32x4 acc[8][4] = {};

  stage(0, 0); stage(1, 1); stage(2, 2);
  asm volatile("s_waitcnt vmcnt(4)" ::: "memory");
  __builtin_amdgcn_s_barrier();
#pragma unroll
  for (int mi = 0; mi < 4; ++mi) aP[mi] = *(const i32x4*)(smem + aoffw + mi * 1024);
#pragma unroll
  for (int ni = 0; ni < 4; ++ni) bP[ni] = *(const i32x4*)(smem + boffw + ni * 1024);

  auto body = [&](int kt, i32x4 (&AY)[4], i32x4 (&BY)[4],
                  i32x4 (&AX)[4], i32x4 (&BX)[4],
                  i32x4 (&a2Y)[4], i32x4 (&a2X)[4], bool doHi) {
    if (doHi) {
#pragma unroll
      for (int mi = 0; mi < 4; ++mi)
#pragma unroll
        for (int ni = 0; ni < 4; ++ni)
          acc[4 + mi][ni] = __builtin_amdgcn_mfma_i32_16x16x64_i8(a2X[mi], BX[ni], acc[4 + mi][ni], 0, 0, 0);
    }
    const int st = (kt + 3 < NT) ? kt + 3 : NT - 1;
    stage(st, (kt + 3) & 3);
    const int ab = (kt & 3) * 32768 + aoffw;
#pragma unroll
    for (int mi = 0; mi < 4; ++mi)
      a2Y[mi] = *(const i32x4*)(smem + ab + 4096 + mi * 1024);
    if (kt + 1 < NT) {
      const int nb = ((kt + 1) & 3) * 32768;
#pragma unroll
      for (int mi = 0; mi < 4; ++mi) AX[mi] = *(const i32x4*)(smem + nb + aoffw + mi * 1024);
#pragma unroll
      for (int ni = 0; ni < 4; ++ni) BX[ni] = *(const i32x4*)(smem + nb + boffw + ni * 1024);
    }
#pragma unroll
    for (int mi = 0; mi < 4; ++mi)
#pragma unroll
      for (int ni = 0; ni < 4; ++ni)
        acc[mi][ni] = __builtin_amdgcn_mfma_i32_16x16x64_i8(AY[mi], BY[ni], acc[mi][ni], 0, 0, 0);
    asm volatile("s_waitcnt lgkmcnt(0)" ::: "memory");
    __builtin_amdgcn_sched_barrier(0);
    asm volatile("s_waitcnt vmcnt(4)" ::: "memory");
    __builtin_amdgcn_s_barrier();
  };

  body(0, aP, bP, aQ, bQ, a2P, a2Q, false);
  for (int kt = 1; kt < NT - 1; kt += 2) {
    body(kt, aQ, bQ, aP, bP, a2Q, a2P, true);
    body(kt + 1, aP, bP, aQ, bQ, a2P, a2Q, true);
  }
  body(NT - 1, aQ, bQ, aP, bP, a2Q, a2P, true);
#pragma unroll
  for (int mi = 0; mi < 4; ++mi)
#pragma unroll
    for (int ni = 0; ni < 4; ++ni)
      acc[4 + mi][ni] = __builtin_amdgcn_mfma_i32_16x16x64_i8(a2Q[mi], bQ[ni], acc[4 + mi][ni], 0, 0, 0);

  asm volatile("s_waitcnt vmcnt(0)" ::: "memory");
  __builtin_amdgcn_s_barrier();

  const int sl_row = lane >> 3;
  const int sl_col = ((lane & 7) ^ (lane >> 3)) << 4;
  auto SBF = [&](const __bf16* g, size_t r0, int ldsoff) {
    char* d0 = smem + ldsoff + w * 2048 + lane * 16;
#pragma unroll
    for (int s = 0; s < 2; ++s) {
      const int rl = (w * 2 + s) * 8 + sl_row;
      gload_lds16((const char*)g + (r0 + rl) * 128 + sl_col, d0 + s * 1024);
    }
  };
  SBF(xa, bm, 0); SBF(xa, bm + 128, 16384);
  SBF(Blt, bn, 32768); SBF(Blt, bn + 128, 49152);

  float sc[4];
#pragma unroll
  for (int ni = 0; ni < 4; ++ni)
    sc[ni] = scale[bn + wc * 64 + ni * 16 + (lane & 15)];
  f32x4 tm[8];
#pragma unroll
  for (int mi = 0; mi < 8; ++mi)
    tm[mi] = *(const f32x4*)&tstep[bm + wr * 128 + mi * 16 + (lane >> 4) * 4];

  asm volatile("s_waitcnt vmcnt(0)" ::: "memory");
  __builtin_amdgcn_s_barrier();

  const int cx0 = ((lane >> 4) << 4) ^ ((lane & 7) << 4);
  const int cx1 = (64 | ((lane >> 4) << 4)) ^ ((lane & 7) << 4);
  const int abE = wr * 16384 + (lane & 15) * 128;
  const int bbE = 32768 + (wc >> 1) * 16384 + ((wc & 1) * 64 + (lane & 15)) * 128;

  bf16x8 bl0[4], bl1[4];
#pragma unroll
  for (int ni = 0; ni < 4; ++ni) {
    bl0[ni] = *(const bf16x8*)(smem + bbE + ni * 2048 + cx0);
    bl1[ni] = *(const bf16x8*)(smem + bbE + ni * 2048 + cx1);
  }
#pragma unroll
  for (int mi = 0; mi < 8; ++mi) {
    bf16x8 ax0 = *(const bf16x8*)(smem + abE + mi * 2048 + cx0);
    bf16x8 ax1 = *(const bf16x8*)(smem + abE + mi * 2048 + cx1);
    const size_t row = bm + wr * 128 + mi * 16 + (lane >> 4) * 4;
#pragma unroll
    for (int ni = 0; ni < 4; ++ni) {
      f32x4 l = {0.f, 0.f, 0.f, 0.f};
      l = __builtin_amdgcn_mfma_f32_16x16x32_bf16(ax0, bl0[ni], l, 0, 0, 0);
      l = __builtin_amdgcn_mfma_f32_16x16x32_bf16(ax1, bl1[ni], l, 0, 0, 0);
      const size_t col = bn + wc * 64 + ni * 16 + (lane & 15);
#pragma unroll
      for (int j = 0; j < 4; ++j)
        out[(row + j) * DOUT + col] = (float)acc[mi][ni][j] * (sc[ni] * tm[mi][j]) + l[j];
    }
  }
}

extern "C" void kernel_launch(void* const* d_in, const int* in_sizes, int n_in,
                              void* d_out, int out_size, void* d_ws, size_t ws_size,
                              hipStream_t stream) {
  const float* x = (const float*)d_in[0];
  const int* qw = (const int*)d_in[1];
  const float* scale = (const float*)d_in[2];
  const float* lA = (const float*)d_in[3];
  const float* lB = (const float*)d_in[4];
  float* out = (float*)d_out;

  char* ws = (char*)d_ws;
  signed char* Xi8 = (signed char*)ws;                              // 33.6 MB
  signed char* Wi8 = (signed char*)(ws + 33554432);                 // 16.8 MB
  __bf16* xa    = (__bf16*)(ws + 50331648);                         // 1.05 MB
  signed char* Ai8 = (signed char*)(ws + 51380224);                 // 0.26 MB
  __bf16* Blt   = (__bf16*)(ws + 51904512);                         // 0.52 MB
  float* tstep  = (float*)(ws + 52428800);                          // 32 KB
  float* astep  = (float*)(ws + 52461568);                          // 256 B

  hipFuncSetAttribute((const void*)gemm_i8_kernel,
                      hipFuncAttributeMaxDynamicSharedMemorySize, 131072);

  prep_kernel<<<24896, 256, 0, stream>>>(x, qw, lA, lB, Xi8, tstep, Wi8, Ai8, astep, Blt);
  lora_xa_kernel<<<MTOT / 16, 256, 0, stream>>>(Xi8, tstep, Ai8, astep, xa);
  gemm_i8_kernel<<<(MTOT / 256) * (DOUT / 256), 512, 131072, stream>>>(
      Xi8, Wi8, scale, tstep, xa, Blt, out);
}